// Round 1
// baseline (130.780 us; speedup 1.0000x reference)
//
#include <hip/hip_runtime.h>
#include <math.h>

// QConv2d: new_rho = kron(Ux,Uy) @ rho @ kron(Ux,Uy)^T
// Ux,Uy are 32x32 block-diagonal with four IDENTICAL 8x8 orthogonal blocks
// (Reck triangle of 28 Givens rotations). So the op factorizes into four
// independent length-8 contractions on axes (x1,y1,x2,y2) of
// rho[B,32,32,32,32] (row a = x1*32+y1, col = x2*32+y2), block-diagonal in
// each 32 -> 4 blocks of 8.  Memory-bound: 64MB in + 64MB out.

#define NPHI 28

// ---------------- setup: build the two 8x8 filter unitaries ----------------
__global__ void setup_uf(const float* __restrict__ phi_x,
                         const float* __restrict__ phi_y,
                         float* __restrict__ ws) {
    const int t = threadIdx.x;
    if (t < 2) {
        const float* phi = (t == 0) ? phi_x : phi_y;
        float U[8][8];
#pragma unroll
        for (int i = 0; i < 8; ++i)
#pragma unroll
            for (int j = 0; j < 8; ++j) U[i][j] = (i == j) ? 1.0f : 0.0f;
        int idx = 0;
#pragma unroll
        for (int i = 1; i < 8; ++i) {
#pragma unroll
            for (int j = i; j >= 1; --j) {
                const float c = cosf(phi[idx]);
                const float s = sinf(phi[idx]);
#pragma unroll
                for (int m = 0; m < 8; ++m) {
                    const float a = U[j - 1][m], b = U[j][m];
                    U[j - 1][m] = c * a + s * b;
                    U[j][m]     = -s * a + c * b;
                }
                ++idx;
            }
        }
        float* o = ws + t * 64;
#pragma unroll
        for (int i = 0; i < 8; ++i)
#pragma unroll
            for (int j = 0; j < 8; ++j) o[i * 8 + j] = U[i][j];
    }
}

// ---------------- fused 4-axis contraction ----------------
// LDS layout: padded float index P(f) = 9*(f>>3) + (f&7), f = ((x1m*8+y1m)*8+x2m)*8+y2m
// -> strides per contraction axis: x1m:576  y1m:72  x2m:9  y2m:1 (all ~conflict-free)

#define CONTRACT_PHASE(UFSRC, P0_EXPR, STRIDE)                                 \
    {                                                                          \
        float uf[64];                                                          \
        _Pragma("unroll")                                                      \
        for (int m = 0; m < 64; ++m) uf[m] = (UFSRC)[m];                       \
        _Pragma("unroll 1")                                                    \
        for (int jj = 0; jj < 8; ++jj) {                                       \
            const int g  = t + 64 * jj;                                        \
            const int P0 = (P0_EXPR);                                          \
            float in[8], o[8];                                                 \
            _Pragma("unroll")                                                  \
            for (int k = 0; k < 8; ++k) in[k] = S[P0 + (STRIDE) * k];          \
            _Pragma("unroll")                                                  \
            for (int i = 0; i < 8; ++i) {                                      \
                float acc = 0.0f;                                              \
                _Pragma("unroll")                                              \
                for (int k = 0; k < 8; ++k)                                    \
                    acc = fmaf(uf[i * 8 + k], in[k], acc);                     \
                o[i] = acc;                                                    \
            }                                                                  \
            _Pragma("unroll")                                                  \
            for (int i = 0; i < 8; ++i) S[P0 + (STRIDE) * i] = o[i];           \
        }                                                                      \
    }                                                                          \
    __syncthreads();

__global__ __launch_bounds__(64) void qconv_main(const float* __restrict__ rho,
                                                 const float* __restrict__ ws,
                                                 float* __restrict__ out) {
    __shared__ float S[4608];  // 4096 data + 512 pad = 18KB
    const int t   = threadIdx.x;
    const int blk = blockIdx.x;
    const int b   = blk >> 8;
    const int c   = blk & 255;
    const int bx1 = (c >> 6) & 3, by1 = (c >> 4) & 3;
    const int bx2 = (c >> 2) & 3, by2 = c & 3;

    const float* __restrict__ bin  = rho + (size_t)b * 1048576;
    float* __restrict__       bout = out + (size_t)b * 1048576;
    const float* __restrict__ Ufx  = ws;
    const float* __restrict__ Ufy  = ws + 64;
    const int rowb = bx1 * 256 + by1 * 8;  // row of (x1m=0,y1m=0)
    const int colb = bx2 * 256 + by2 * 8;  // col of (x2m=0,y2m=0)

    // ---- global -> LDS (16 float4 per thread; 32B-chunk coalesced)
#pragma unroll
    for (int v = 0; v < 16; ++v) {
        const int idx4  = t + 64 * v;
        const int chunk = idx4 >> 1;          // (x1m*8+y1m)*8+x2m
        const int half  = (idx4 & 1) * 4;
        const int x2m = chunk & 7, y1m = (chunk >> 3) & 7, x1m = chunk >> 6;
        const int row = rowb + x1m * 32 + y1m;
        const int col = colb + x2m * 32 + half;
        const float4 val = *reinterpret_cast<const float4*>(bin + row * 1024 + col);
        const int P = 9 * chunk + half;       // 4B-aligned scalar writes (pad breaks 16B align)
        S[P + 0] = val.x; S[P + 1] = val.y; S[P + 2] = val.z; S[P + 3] = val.w;
    }
    __syncthreads();

    // phase 1: contract x1m (stride 576 in padded LDS)
    CONTRACT_PHASE(Ufx, 9 * (g >> 3) + (g & 7), 576)
    // phase 2: contract y1m (stride 72)
    CONTRACT_PHASE(Ufy, 9 * ((g >> 6) * 64 + ((g >> 3) & 7)) + (g & 7), 72)
    // phase 3: contract x2m (stride 9)
    CONTRACT_PHASE(Ufx, 72 * (g >> 3) + (g & 7), 9)

    // phase 4: contract y2m (stride 1) fused with global store
    {
        float uf[64];
#pragma unroll
        for (int m = 0; m < 64; ++m) uf[m] = Ufy[m];
#pragma unroll 1
        for (int jj = 0; jj < 8; ++jj) {
            const int g  = t + 64 * jj;       // (x1m*8+y1m)*8+x2m
            const int P0 = 9 * g;
            float in[8], o[8];
#pragma unroll
            for (int k = 0; k < 8; ++k) in[k] = S[P0 + k];
#pragma unroll
            for (int i = 0; i < 8; ++i) {
                float acc = 0.0f;
#pragma unroll
                for (int k = 0; k < 8; ++k) acc = fmaf(uf[i * 8 + k], in[k], acc);
                o[i] = acc;
            }
            const int x2m = g & 7, y1m = (g >> 3) & 7, x1m = g >> 6;
            const int row = rowb + x1m * 32 + y1m;
            const int col = colb + x2m * 32;
            float* p = bout + row * 1024 + col;
            *reinterpret_cast<float4*>(p)     = make_float4(o[0], o[1], o[2], o[3]);
            *reinterpret_cast<float4*>(p + 4) = make_float4(o[4], o[5], o[6], o[7]);
        }
    }
}

extern "C" void kernel_launch(void* const* d_in, const int* in_sizes, int n_in,
                              void* d_out, int out_size, void* d_ws, size_t ws_size,
                              hipStream_t stream) {
    const float* rho   = (const float*)d_in[0];
    const float* phi_x = (const float*)d_in[1];
    const float* phi_y = (const float*)d_in[2];
    float* out = (float*)d_out;
    float* ws  = (float*)d_ws;

    setup_uf<<<1, 64, 0, stream>>>(phi_x, phi_y, ws);
    qconv_main<<<4096, 64, 0, stream>>>(rho, ws, out);
}

// Round 2
// 59.366 us; speedup vs baseline: 2.2030x; 2.2030x over previous
//
#include <hip/hip_runtime.h>
#include <math.h>

// QConv2d: new_rho = kron(Ux,Uy) @ rho @ kron(Ux,Uy)^T
// Ux,Uy are 32x32 block-diagonal with four IDENTICAL 8x8 orthogonal blocks.
// rho[B,32,32,32,32]: row a = x1*32+y1, col c = x2*32+y2, each axis block-
// diagonal in groups of 8. Four independent length-8 contractions.
//
// Layout: block = (b, bx1, by1, bx2): 64 rows x 256 contiguous cols.
//  - thread t owns column bx2*256+t: loads 64 rows coalesced (dword),
//    contracts y1 and x1 fully in registers (1024 FMA),
//  - XOR-swizzled LDS transpose (64KB),
//  - thread (r=t&63, by2=t>>6) contracts y2 and x2 in registers,
//  - write back via LDS, store coalesced.

__global__ void setup_uf(const float* __restrict__ phi_x,
                         const float* __restrict__ phi_y,
                         float* __restrict__ ws) {
    const int t = threadIdx.x;
    if (t < 2) {
        const float* phi = (t == 0) ? phi_x : phi_y;
        float U[8][8];
#pragma unroll
        for (int i = 0; i < 8; ++i)
#pragma unroll
            for (int j = 0; j < 8; ++j) U[i][j] = (i == j) ? 1.0f : 0.0f;
        int idx = 0;
#pragma unroll
        for (int i = 1; i < 8; ++i) {
#pragma unroll
            for (int j = i; j >= 1; --j) {
                const float c = cosf(phi[idx]);
                const float s = sinf(phi[idx]);
#pragma unroll
                for (int m = 0; m < 8; ++m) {
                    const float a = U[j - 1][m], b = U[j][m];
                    U[j - 1][m] = c * a + s * b;
                    U[j][m]     = -s * a + c * b;
                }
                ++idx;
            }
        }
        float* o = ws + t * 64;
#pragma unroll
        for (int i = 0; i < 8; ++i)
#pragma unroll
            for (int j = 0; j < 8; ++j) o[i * 8 + j] = U[i][j];
    }
}

// swizzled LDS address: row-major [64][256] with col XOR'd by row&31
// -> cross-row (fixed-col) access and in-row access are both conflict-free.
#define SWZ(row, col) (((row) << 8) + ((col) ^ ((row) & 31)))

// contract the INNER index (stride 1 within groups of 8) of a[64] with M[8][8]
#define CONTRACT_INNER(M, a)                                                   \
    _Pragma("unroll")                                                          \
    for (int _g = 0; _g < 8; ++_g) {                                           \
        float _tmp[8];                                                         \
        _Pragma("unroll")                                                      \
        for (int _i = 0; _i < 8; ++_i) {                                       \
            float _acc = 0.0f;                                                 \
            _Pragma("unroll")                                                  \
            for (int _k = 0; _k < 8; ++_k)                                     \
                _acc = fmaf((M)[_i * 8 + _k], (a)[_g * 8 + _k], _acc);         \
            _tmp[_i] = _acc;                                                   \
        }                                                                      \
        _Pragma("unroll")                                                      \
        for (int _i = 0; _i < 8; ++_i) (a)[_g * 8 + _i] = _tmp[_i];            \
    }

// contract the OUTER index (stride 8) of a[64] with M[8][8]
#define CONTRACT_OUTER(M, a)                                                   \
    _Pragma("unroll")                                                          \
    for (int _g = 0; _g < 8; ++_g) {                                           \
        float _tmp[8];                                                         \
        _Pragma("unroll")                                                      \
        for (int _i = 0; _i < 8; ++_i) {                                       \
            float _acc = 0.0f;                                                 \
            _Pragma("unroll")                                                  \
            for (int _k = 0; _k < 8; ++_k)                                     \
                _acc = fmaf((M)[_i * 8 + _k], (a)[_k * 8 + _g], _acc);         \
            _tmp[_i] = _acc;                                                   \
        }                                                                      \
        _Pragma("unroll")                                                      \
        for (int _i = 0; _i < 8; ++_i) (a)[_i * 8 + _g] = _tmp[_i];            \
    }

__global__ __launch_bounds__(256) void qconv_fused(const float* __restrict__ rho,
                                                   const float* __restrict__ ws,
                                                   float* __restrict__ out) {
    __shared__ float S[16384];  // 64 rows x 256 cols = 64 KB (swizzled)
    const int t   = threadIdx.x;
    const int bid = blockIdx.x;
    const int bx2 = bid & 3;
    const int by1 = (bid >> 2) & 3;
    const int bx1 = (bid >> 4) & 3;
    const int b   = bid >> 6;

    const float* __restrict__ UX = ws;       // Ufx[8][8]
    const float* __restrict__ UY = ws + 64;  // Ufy[8][8]

    const size_t B0      = (size_t)b << 20;  // b * 1024*1024
    const int    rowbase = bx1 * 256 + by1 * 8;
    const int    cg      = bx2 * 256 + t;    // global column owned by thread

    // ---- load 64 rows at column cg (coalesced dwords) ----
    float v[64];
#pragma unroll
    for (int x = 0; x < 8; ++x)
#pragma unroll
        for (int y = 0; y < 8; ++y)
            v[x * 8 + y] = rho[B0 + (size_t)(rowbase + x * 32 + y) * 1024 + cg];

    // ---- row transform in registers: contract y1 (inner), then x1 (outer) ----
    CONTRACT_INNER(UY, v)
    CONTRACT_OUTER(UX, v)

    // ---- stage to LDS: logical (row j, col t) ----
#pragma unroll
    for (int j = 0; j < 64; ++j) S[SWZ(j, t)] = v[j];
    __syncthreads();

    // ---- transposed view: thread handles LDS row r, col-group by2 ----
    const int r   = t & 63;
    const int by2 = t >> 6;
    const int cb  = by2 * 8;
    float p[64];
#pragma unroll
    for (int x = 0; x < 8; ++x)
#pragma unroll
        for (int y = 0; y < 8; ++y)
            p[x * 8 + y] = S[SWZ(r, x * 32 + cb + y)];

    // ---- col transform in registers: contract y2 (inner), then x2 (outer) ----
    CONTRACT_INNER(UY, p)
    CONTRACT_OUTER(UX, p)

    // ---- write back to LDS ----
#pragma unroll
    for (int x = 0; x < 8; ++x)
#pragma unroll
        for (int y = 0; y < 8; ++y)
            S[SWZ(r, x * 32 + cb + y)] = p[x * 8 + y];
    __syncthreads();

    // ---- store 64 rows at column cg (coalesced dwords) ----
#pragma unroll
    for (int x = 0; x < 8; ++x)
#pragma unroll
        for (int y = 0; y < 8; ++y)
            out[B0 + (size_t)(rowbase + x * 32 + y) * 1024 + cg] =
                S[SWZ(x * 8 + y, t)];
}

extern "C" void kernel_launch(void* const* d_in, const int* in_sizes, int n_in,
                              void* d_out, int out_size, void* d_ws, size_t ws_size,
                              hipStream_t stream) {
    const float* rho   = (const float*)d_in[0];
    const float* phi_x = (const float*)d_in[1];
    const float* phi_y = (const float*)d_in[2];
    float* out = (float*)d_out;
    float* ws  = (float*)d_ws;

    setup_uf<<<1, 64, 0, stream>>>(phi_x, phi_y, ws);
    qconv_fused<<<1024, 256, 0, stream>>>(rho, ws, out);
}